// Round 24
// baseline (70.908 us; speedup 1.0000x reference)
//
#include <hip/hip_runtime.h>

#define FDIM  256
#define H1D   256
#define H2D   128
#define BATCH 4096

typedef _Float16 half2v __attribute__((ext_vector_type(2)));

#define ROW_U32    132                       // 64 (A,C) u32 pairs + 4 pad (16B-aligned rows)
#define NROWS      257
#define DLDS_U32   (NROWS * ROW_U32)         // 33,924
#define DLDS_BYTES (DLDS_U32 * 4)            // 135,696

#define XT_BYTES   ((size_t)FDIM * BATCH * 4)
#define W3H_BYTES  ((size_t)FDIM * 64 * 4)

#define SEG    8
#define SEGLEN 32

union U32H2 { unsigned u; half2v h; };
union H16U { _Float16 h; unsigned short u; };

// DPP helpers: cross-lane on the VALU pipe (not DS). bound_ctrl=true -> 0 fill.
#define DPP_ADD_F(v, ctrl)                                                   \
    ((v) + __int_as_float(__builtin_amdgcn_update_dpp(                       \
               0, __float_as_int(v), (ctrl), 0xf, 0xf, true)))
#define DPP_GET_I(x, ctrl)                                                   \
    __builtin_amdgcn_update_dpp(0, (int)(x), (ctrl), 0xf, 0xf, true)
// ctrl: quad_perm[1,0,3,2]=0xB1 (xor1), [2,3,0,1]=0x4E (xor2),
//       row_ror:4=0x124, row_ror:8=0x128 (rotation -> total in ALL lanes).

// ---------------------------------------------------------------------------
// prep2: [0,256): x (B,F) f32 -> xT (F,B) f32 transpose.
//        [256,320): W3 f32 -> f16-pair packed w3h[f][64].
// ---------------------------------------------------------------------------
__global__ __launch_bounds__(256) void prep2(const float* __restrict__ x,
                                             const float* __restrict__ W3,
                                             float* __restrict__ xT,
                                             unsigned* __restrict__ w3h) {
    const int bid = blockIdx.x, tid = threadIdx.x;
    if (bid < 256) {
        __shared__ float tile[64][65];
        const int bt = bid >> 2, ft = bid & 3;
        const int tr = tid >> 2, c0 = (tid & 3) * 16;
#pragma unroll
        for (int j = 0; j < 4; ++j) {
            const float4 v = *(const float4*)(
                x + (size_t)(bt * 64 + tr) * FDIM + ft * 64 + c0 + j * 4);
            tile[tr][c0 + j * 4 + 0] = v.x;
            tile[tr][c0 + j * 4 + 1] = v.y;
            tile[tr][c0 + j * 4 + 2] = v.z;
            tile[tr][c0 + j * 4 + 3] = v.w;
        }
        __syncthreads();
        const int fr = tid >> 2, bb = (tid & 3) * 16;
#pragma unroll
        for (int j = 0; j < 4; ++j) {
            float4 o;
            o.x = tile[bb + j * 4 + 0][fr];
            o.y = tile[bb + j * 4 + 1][fr];
            o.z = tile[bb + j * 4 + 2][fr];
            o.w = tile[bb + j * 4 + 3][fr];
            *(float4*)(xT + (size_t)(ft * 64 + fr) * BATCH + bt * 64 + bb + j * 4) = o;
        }
    } else {
        const int idx = (bid - 256) * 256 + tid;    // 0..16383
        const int f = idx >> 6, p = idx & 63;
        U32H2 u;
        u.h[0] = (_Float16)W3[f * H2D + 2 * p];
        u.h[1] = (_Float16)W3[f * H2D + 2 * p + 1];
        w3h[f * 64 + p] = u.u;
    }
}

// ---------------------------------------------------------------------------
// Fused build+eval (R23 + register unlock):
// __launch_bounds__(1024, 4): dynamic-LDS kernels default to a 8-wave/SIMD
// register target (VGPR=32 observed) because the compiler can't see that
// 132.5 KB LDS forces 1 block/CU. Declaring 4 waves/EU raises the cap to
// 128 VGPRs -> E1's b128 loads and Pass A/B's unroll-8 global loads can
// actually pipeline. E1 unroll deepened to use the headroom.
// ---------------------------------------------------------------------------
__global__ __launch_bounds__(1024, 4) void coxnam_fused(
    const float* __restrict__ W1, const float* __restrict__ b1,
    const float* __restrict__ W2, const float* __restrict__ b2,
    const float* __restrict__ xT, const unsigned* __restrict__ w3h,
    float* __restrict__ partial) {
    extern __shared__ unsigned rlds[];          // 33,924 u32 = 132.5 KB
    __shared__ float t_s[256], w1_s[256], b1_s[256], ts2[256];
    __shared__ int id_s[256];
    __shared__ unsigned scratch[SEG * 128 * 4]; // 16 KB: ranks / SA..BC / c-pack
    float* SA = (float*)scratch;
    float* SC = SA + SEG * 128;
    float* BA = SC + SEG * 128;
    float* BC = BA + SEG * 128;
    const int f = blockIdx.x, tid = threadIdx.x;

    if (tid < 256) {
        const float w = W1[f * H1D + tid];
        const float bb = b1[f * H1D + tid];
        w1_s[tid] = w;
        b1_s[tid] = bb;
        t_s[tid] = (w != 0.f) ? (-bb / w) : __builtin_inff();
    }
    __syncthreads();

    // ---- rank-sort ----
    {
        const int kq = tid >> 8, kk = tid & 255;
        const float tk = t_s[kk];
        int r = 0;
        const int k0 = kq * 64;
#pragma unroll 16
        for (int k2 = k0; k2 < k0 + 64; ++k2) {
            const float t2 = t_s[k2];
            r += (t2 < tk || (t2 == tk && k2 < kk)) ? 1 : 0;
        }
        scratch[kq * 256 + kk] = (unsigned)r;
    }
    __syncthreads();
    if (tid < 256) {
        const int r = (int)(scratch[tid] + scratch[256 + tid] +
                            scratch[512 + tid] + scratch[768 + tid]);
        ts2[r] = t_s[tid];
        id_s[r] = tid;
    }
    __syncthreads();

    const int seg = tid >> 7, n = tid & 127;
    const float* w2p = W2 + (size_t)f * H1D * H2D;

    // ---- Pass A ----
    {
        float sa = 0.f, sc = 0.f, ba = 0.f, bc = 0.f;
#pragma unroll 8
        for (int ii = 0; ii < SEGLEN; ++ii) {
            const int kk = id_s[seg * SEGLEN + ii];
            const float ws = w1_s[kk], bs = b1_s[kk];
            const float w2s = w2p[kk * H2D + n];
            if (ws < 0.f) { ba += ws * w2s; bc += bs * w2s; }
            else if (ws == 0.f && bs > 0.f) bc += bs * w2s;
            const float dA = (ws > 0.f) ? ws : ((ws < 0.f) ? -ws : 0.f);
            const float dC = (ws > 0.f) ? bs : ((ws < 0.f) ? -bs : 0.f);
            sa += dA * w2s;
            sc += dC * w2s;
        }
        SA[seg * 128 + n] = sa; SC[seg * 128 + n] = sc;
        BA[seg * 128 + n] = ba; BC[seg * 128 + n] = bc;
    }
    __syncthreads();

    // ---- offsets + Pass B (DPP-paired uint2 writes) ----
    {
        float baseA = 0.f, baseC = b2[f * H2D + n];
#pragma unroll
        for (int s = 0; s < SEG; ++s) {
            baseA += BA[s * 128 + n];
            baseC += BC[s * 128 + n];
        }
        float A = baseA, C = baseC;
        for (int s = 0; s < seg; ++s) {
            A += SA[s * 128 + n];
            C += SC[s * 128 + n];
        }
        const int pr = n >> 1;
        const bool wr = ((n & 1) == 0);
        if (seg == 0) {
            H16U ah, ch;
            ah.h = (_Float16)baseA;
            ch.h = (_Float16)baseC;
            const unsigned ao = (unsigned)DPP_GET_I(ah.u, 0xB1);
            const unsigned co = (unsigned)DPP_GET_I(ch.u, 0xB1);
            if (wr) {
                uint2 v;
                v.x = (unsigned)ah.u | (ao << 16);
                v.y = (unsigned)ch.u | (co << 16);
                *(uint2*)(rlds + pr * 2) = v;
            }
        }
#pragma unroll 8
        for (int ii = 0; ii < SEGLEN; ++ii) {
            const int i = seg * SEGLEN + ii + 1;    // rows 1..256
            const int kk = id_s[i - 1];
            const float ws = w1_s[kk], bs = b1_s[kk];
            const float w2s = w2p[kk * H2D + n];
            const float dA = (ws > 0.f) ? ws : ((ws < 0.f) ? -ws : 0.f);
            const float dC = (ws > 0.f) ? bs : ((ws < 0.f) ? -bs : 0.f);
            A += dA * w2s;
            C += dC * w2s;
            H16U ah, ch;
            ah.h = (_Float16)A;
            ch.h = (_Float16)C;
            const unsigned ao = (unsigned)DPP_GET_I(ah.u, 0xB1);
            const unsigned co = (unsigned)DPP_GET_I(ch.u, 0xB1);
            if (wr) {
                uint2 v;
                v.x = (unsigned)ah.u | (ao << 16);
                v.y = (unsigned)ch.u | (co << 16);
                *(uint2*)(rlds + i * ROW_U32 + pr * 2) = v;
            }
        }
    }
    __syncthreads();   // rows done; scratch free for c-pack

    // ---- E0: per-b interval search, pack (c | f16(xv)<<16) ----
#pragma unroll
    for (int rd = 0; rd < 4; ++rd) {
        const int b = rd * 1024 + tid;
        const float xv = xT[(size_t)f * BATCH + b];
        int c = 0;
#pragma unroll
        for (int s = 256; s >= 1; s >>= 1) {
            const int m = c + s;
            if (m <= 256 && ts2[m - 1] <= xv) c = m;
        }
        H16U hx;
        hx.h = (_Float16)xv;
        scratch[b] = (unsigned)c | ((unsigned)hx.u << 16);
    }
    __syncthreads();

    // ---- E1: 16-lane groups; DS = 2 b128 + 1 scratch read per b;
    //      DPP reduce on VALU; unroll 4 pairs (8 b's) for load ILP ----
    const int grp = tid >> 4, gl = tid & 15;
    const unsigned* wp = w3h + f * 64;
    const uint2 w3q0 = *(const uint2*)(wp + 2 * gl);
    const uint2 w3q1 = *(const uint2*)(wp + 32 + 2 * gl);
    const half2v z2 = {(_Float16)0.f, (_Float16)0.f};
#pragma unroll 4
    for (int p = 0; p < 64; p += 2) {
        const int b0 = p * 64 + grp;
        const int b1i = (p + 1) * 64 + grp;
        const unsigned ci0 = scratch[b0];
        const unsigned ci1 = scratch[b1i];
        const unsigned* rp0 = rlds + (ci0 & 0xffffu) * ROW_U32;
        const unsigned* rp1 = rlds + (ci1 & 0xffffu) * ROW_U32;
        // issue all 4 b128 loads up front (ILP)
        const uint4 v00 = *(const uint4*)(rp0 + 4 * gl);
        const uint4 v01 = *(const uint4*)(rp0 + 4 * gl + 64);
        const uint4 v10 = *(const uint4*)(rp1 + 4 * gl);
        const uint4 v11 = *(const uint4*)(rp1 + 4 * gl + 64);
        U32H2 xv0, xv1;
        xv0.u = (ci0 >> 16) | (ci0 & 0xffff0000u);
        xv1.u = (ci1 >> 16) | (ci1 & 0xffff0000u);
        float c0a = 0.f, c1a = 0.f;
        {
            U32H2 a0, cc0, a1, cc1, w30, w31;
            a0.u = v00.x; cc0.u = v00.y; a1.u = v00.z; cc1.u = v00.w;
            w30.u = w3q0.x; w31.u = w3q0.y;
            half2v h0 = __builtin_elementwise_max(xv0.h * a0.h + cc0.h, z2);
            half2v h1 = __builtin_elementwise_max(xv0.h * a1.h + cc1.h, z2);
            c0a = __builtin_amdgcn_fdot2(h0, w30.h, c0a, false);
            c0a = __builtin_amdgcn_fdot2(h1, w31.h, c0a, false);
            a0.u = v01.x; cc0.u = v01.y; a1.u = v01.z; cc1.u = v01.w;
            w30.u = w3q1.x; w31.u = w3q1.y;
            h0 = __builtin_elementwise_max(xv0.h * a0.h + cc0.h, z2);
            h1 = __builtin_elementwise_max(xv0.h * a1.h + cc1.h, z2);
            c0a = __builtin_amdgcn_fdot2(h0, w30.h, c0a, false);
            c0a = __builtin_amdgcn_fdot2(h1, w31.h, c0a, false);
        }
        {
            U32H2 a0, cc0, a1, cc1, w30, w31;
            a0.u = v10.x; cc0.u = v10.y; a1.u = v10.z; cc1.u = v10.w;
            w30.u = w3q0.x; w31.u = w3q0.y;
            half2v h0 = __builtin_elementwise_max(xv1.h * a0.h + cc0.h, z2);
            half2v h1 = __builtin_elementwise_max(xv1.h * a1.h + cc1.h, z2);
            c1a = __builtin_amdgcn_fdot2(h0, w30.h, c1a, false);
            c1a = __builtin_amdgcn_fdot2(h1, w31.h, c1a, false);
            a0.u = v11.x; cc0.u = v11.y; a1.u = v11.z; cc1.u = v11.w;
            w30.u = w3q1.x; w31.u = w3q1.y;
            h0 = __builtin_elementwise_max(xv1.h * a0.h + cc0.h, z2);
            h1 = __builtin_elementwise_max(xv1.h * a1.h + cc1.h, z2);
            c1a = __builtin_amdgcn_fdot2(h0, w30.h, c1a, false);
            c1a = __builtin_amdgcn_fdot2(h1, w31.h, c1a, false);
        }
        // DPP reduce within each 16-lane row (VALU pipe); ror -> all lanes
        c0a = DPP_ADD_F(c0a, 0xB1);
        c0a = DPP_ADD_F(c0a, 0x4E);
        c0a = DPP_ADD_F(c0a, 0x124);
        c0a = DPP_ADD_F(c0a, 0x128);
        c1a = DPP_ADD_F(c1a, 0xB1);
        c1a = DPP_ADD_F(c1a, 0x4E);
        c1a = DPP_ADD_F(c1a, 0x124);
        c1a = DPP_ADD_F(c1a, 0x128);
        if (gl == 0) {
            partial[(size_t)f * BATCH + b0] = c0a;
            partial[(size_t)f * BATCH + b1i] = c1a;
        }
    }
}

// ---------------------------------------------------------------------------
// Final reduction over 256 per-feature partials + sum of b3.
// ---------------------------------------------------------------------------
__global__ __launch_bounds__(256) void reduce_out(const float* __restrict__ partial,
                                                  const float* __restrict__ b3,
                                                  float* __restrict__ out) {
    const int b = blockIdx.x * 256 + threadIdx.x;
    float v = 0.f;
    for (int p = 0; p < FDIM; ++p) v += partial[(size_t)p * BATCH + b];
    float sb3 = 0.f;
#pragma unroll 4
    for (int f4 = 0; f4 < FDIM; f4 += 4) {
        const float4 t = *(const float4*)(b3 + f4);
        sb3 += t.x + t.y + t.z + t.w;
    }
    out[b] = v + sb3;
}

extern "C" void kernel_launch(void* const* d_in, const int* in_sizes, int n_in,
                              void* d_out, int out_size, void* d_ws, size_t ws_size,
                              hipStream_t stream) {
    const float* x  = (const float*)d_in[0];
    const float* W1 = (const float*)d_in[1];
    const float* b1 = (const float*)d_in[2];
    const float* W2 = (const float*)d_in[3];
    const float* b2 = (const float*)d_in[4];
    const float* W3 = (const float*)d_in[5];
    const float* b3 = (const float*)d_in[6];

    float*    xT      = (float*)d_ws;
    unsigned* w3h     = (unsigned*)((char*)xT + XT_BYTES);
    float*    partial = (float*)((char*)w3h + W3H_BYTES);
    const size_t need = XT_BYTES + W3H_BYTES + (size_t)FDIM * BATCH * 4;
    if (ws_size < need) return;  // insufficient scratch; fail visibly

    prep2<<<320, 256, 0, stream>>>(x, W3, xT, w3h);
    coxnam_fused<<<256, 1024, DLDS_BYTES, stream>>>(W1, b1, W2, b2, xT, w3h,
                                                    partial);
    reduce_out<<<BATCH / 256, 256, 0, stream>>>(partial, b3, (float*)d_out);
}

// Round 25
// 68.365 us; speedup vs baseline: 1.0372x; 1.0372x over previous
//
#include <hip/hip_runtime.h>

#define FDIM  256
#define H1D   256
#define H2D   128
#define BATCH 4096

typedef _Float16 half2v __attribute__((ext_vector_type(2)));

#define ROW_U32    132                       // 64 (A,C) u32 pairs + 4 pad (16B-aligned rows)
#define NROWS      257
#define DLDS_U32   (NROWS * ROW_U32)         // 33,924
#define DLDS_BYTES (DLDS_U32 * 4)            // 135,696

#define SEG    8
#define SEGLEN 32

union U32H2 { unsigned u; half2v h; };
union H16U { _Float16 h; unsigned short u; };

// DPP helpers: cross-lane on the VALU pipe (not DS). bound_ctrl=true -> 0 fill.
#define DPP_ADD_F(v, ctrl)                                                   \
    ((v) + __int_as_float(__builtin_amdgcn_update_dpp(                       \
               0, __float_as_int(v), (ctrl), 0xf, 0xf, true)))
#define DPP_GET_I(x, ctrl)                                                   \
    __builtin_amdgcn_update_dpp(0, (int)(x), (ctrl), 0xf, 0xf, true)
// ctrl: quad_perm[1,0,3,2]=0xB1 (xor1), [2,3,0,1]=0x4E (xor2),
//       row_ror:4=0x124, row_ror:8=0x128 (rotation -> total in ALL lanes).

// ---------------------------------------------------------------------------
// Fused build+eval, fully self-contained (prep2 folded in):
// BUILD: rank-sort (3 barriers); Pass A (sorted walk, base folded, 1 W2
//   load/iter); offsets -> regs; barrier; E0 (per-b search, DIRECT strided
//   x reads - x is L2-resident - packing (c | f16(xv)<<16) into scratch)
//   runs BEFORE Pass B in the same barrier interval so its global-x latency
//   overlaps Pass B's W2 latency; Pass B: DPP-paired uint2 row writes.
// EVAL: E1: 16-lane groups, 2x b128/b-pair, W3 loaded as 2 coalesced
//   float4/lane and packed to f16 in regs, 4 fdot2, DPP-ror reduce.
// ---------------------------------------------------------------------------
__global__ __launch_bounds__(1024, 4) void coxnam_fused(
    const float* __restrict__ W1, const float* __restrict__ b1,
    const float* __restrict__ W2, const float* __restrict__ b2,
    const float* __restrict__ x,  const float* __restrict__ W3,
    float* __restrict__ partial) {
    extern __shared__ unsigned rlds[];          // 33,924 u32 = 132.5 KB
    __shared__ float t_s[256], w1_s[256], b1_s[256], ts2[256];
    __shared__ int id_s[256];
    __shared__ unsigned scratch[SEG * 128 * 4]; // 16 KB: ranks / SA..BC / c-pack
    float* SA = (float*)scratch;
    float* SC = SA + SEG * 128;
    float* BA = SC + SEG * 128;
    float* BC = BA + SEG * 128;
    const int f = blockIdx.x, tid = threadIdx.x;

    if (tid < 256) {
        const float w = W1[f * H1D + tid];
        const float bb = b1[f * H1D + tid];
        w1_s[tid] = w;
        b1_s[tid] = bb;
        t_s[tid] = (w != 0.f) ? (-bb / w) : __builtin_inff();
    }
    __syncthreads();

    // ---- rank-sort ----
    {
        const int kq = tid >> 8, kk = tid & 255;
        const float tk = t_s[kk];
        int r = 0;
        const int k0 = kq * 64;
#pragma unroll 16
        for (int k2 = k0; k2 < k0 + 64; ++k2) {
            const float t2 = t_s[k2];
            r += (t2 < tk || (t2 == tk && k2 < kk)) ? 1 : 0;
        }
        scratch[kq * 256 + kk] = (unsigned)r;
    }
    __syncthreads();
    if (tid < 256) {
        const int r = (int)(scratch[tid] + scratch[256 + tid] +
                            scratch[512 + tid] + scratch[768 + tid]);
        ts2[r] = t_s[tid];
        id_s[r] = tid;
    }
    __syncthreads();

    const int seg = tid >> 7, n = tid & 127;
    const float* w2p = W2 + (size_t)f * H1D * H2D;

    // ---- Pass A ----
    {
        float sa = 0.f, sc = 0.f, ba = 0.f, bc = 0.f;
#pragma unroll 8
        for (int ii = 0; ii < SEGLEN; ++ii) {
            const int kk = id_s[seg * SEGLEN + ii];
            const float ws = w1_s[kk], bs = b1_s[kk];
            const float w2s = w2p[kk * H2D + n];
            if (ws < 0.f) { ba += ws * w2s; bc += bs * w2s; }
            else if (ws == 0.f && bs > 0.f) bc += bs * w2s;
            const float dA = (ws > 0.f) ? ws : ((ws < 0.f) ? -ws : 0.f);
            const float dC = (ws > 0.f) ? bs : ((ws < 0.f) ? -bs : 0.f);
            sa += dA * w2s;
            sc += dC * w2s;
        }
        SA[seg * 128 + n] = sa; SC[seg * 128 + n] = sc;
        BA[seg * 128 + n] = ba; BC[seg * 128 + n] = bc;
    }
    __syncthreads();

    // ---- offsets -> registers (scratch reads complete after this) ----
    float baseA = 0.f, baseC = b2[f * H2D + n];
#pragma unroll
    for (int s = 0; s < SEG; ++s) {
        baseA += BA[s * 128 + n];
        baseC += BC[s * 128 + n];
    }
    float A = baseA, C = baseC;
    for (int s = 0; s < seg; ++s) {
        A += SA[s * 128 + n];
        C += SC[s * 128 + n];
    }
    __syncthreads();   // scratch reads done; cpack writes may begin

    // ---- E0: per-b search (direct strided x reads), pack into scratch.
    //      Placed BEFORE Pass B: its global-x latency overlaps Pass B's
    //      W2 latency within this barrier interval. ----
#pragma unroll
    for (int rd = 0; rd < 4; ++rd) {
        const int b = rd * 1024 + tid;
        const float xv = x[(size_t)b * FDIM + f];
        int c = 0;
#pragma unroll
        for (int s = 256; s >= 1; s >>= 1) {
            const int m = c + s;
            if (m <= 256 && ts2[m - 1] <= xv) c = m;
        }
        H16U hx;
        hx.h = (_Float16)xv;
        scratch[b] = (unsigned)c | ((unsigned)hx.u << 16);
    }

    // ---- Pass B (DPP-paired uint2 writes into rlds rows) ----
    {
        const int pr = n >> 1;
        const bool wr = ((n & 1) == 0);
        if (seg == 0) {
            H16U ah, ch;
            ah.h = (_Float16)baseA;
            ch.h = (_Float16)baseC;
            const unsigned ao = (unsigned)DPP_GET_I(ah.u, 0xB1);
            const unsigned co = (unsigned)DPP_GET_I(ch.u, 0xB1);
            if (wr) {
                uint2 v;
                v.x = (unsigned)ah.u | (ao << 16);
                v.y = (unsigned)ch.u | (co << 16);
                *(uint2*)(rlds + pr * 2) = v;
            }
        }
#pragma unroll 8
        for (int ii = 0; ii < SEGLEN; ++ii) {
            const int i = seg * SEGLEN + ii + 1;    // rows 1..256
            const int kk = id_s[i - 1];
            const float ws = w1_s[kk], bs = b1_s[kk];
            const float w2s = w2p[kk * H2D + n];
            const float dA = (ws > 0.f) ? ws : ((ws < 0.f) ? -ws : 0.f);
            const float dC = (ws > 0.f) ? bs : ((ws < 0.f) ? -bs : 0.f);
            A += dA * w2s;
            C += dC * w2s;
            H16U ah, ch;
            ah.h = (_Float16)A;
            ch.h = (_Float16)C;
            const unsigned ao = (unsigned)DPP_GET_I(ah.u, 0xB1);
            const unsigned co = (unsigned)DPP_GET_I(ch.u, 0xB1);
            if (wr) {
                uint2 v;
                v.x = (unsigned)ah.u | (ao << 16);
                v.y = (unsigned)ch.u | (co << 16);
                *(uint2*)(rlds + i * ROW_U32 + pr * 2) = v;
            }
        }
    }
    __syncthreads();   // rows + cpack both visible

    // ---- E1: 16-lane groups; W3 from 2 coalesced float4 -> f16 regs;
    //      2 b128 + 1 scratch read per b; DPP-ror reduce on VALU ----
    const int grp = tid >> 4, gl = tid & 15;
    const float4 wva = *(const float4*)(W3 + f * H2D + 4 * gl);
    const float4 wvb = *(const float4*)(W3 + f * H2D + 64 + 4 * gl);
    U32H2 w3q0x, w3q0y, w3q1x, w3q1y;
    w3q0x.h[0] = (_Float16)wva.x; w3q0x.h[1] = (_Float16)wva.y;
    w3q0y.h[0] = (_Float16)wva.z; w3q0y.h[1] = (_Float16)wva.w;
    w3q1x.h[0] = (_Float16)wvb.x; w3q1x.h[1] = (_Float16)wvb.y;
    w3q1y.h[0] = (_Float16)wvb.z; w3q1y.h[1] = (_Float16)wvb.w;
    const half2v z2 = {(_Float16)0.f, (_Float16)0.f};
#pragma unroll 4
    for (int p = 0; p < 64; p += 2) {
        const int b0 = p * 64 + grp;
        const int b1i = (p + 1) * 64 + grp;
        const unsigned ci0 = scratch[b0];
        const unsigned ci1 = scratch[b1i];
        const unsigned* rp0 = rlds + (ci0 & 0xffffu) * ROW_U32;
        const unsigned* rp1 = rlds + (ci1 & 0xffffu) * ROW_U32;
        // issue all 4 b128 loads up front (ILP)
        const uint4 v00 = *(const uint4*)(rp0 + 4 * gl);
        const uint4 v01 = *(const uint4*)(rp0 + 4 * gl + 64);
        const uint4 v10 = *(const uint4*)(rp1 + 4 * gl);
        const uint4 v11 = *(const uint4*)(rp1 + 4 * gl + 64);
        U32H2 xv0, xv1;
        xv0.u = (ci0 >> 16) | (ci0 & 0xffff0000u);
        xv1.u = (ci1 >> 16) | (ci1 & 0xffff0000u);
        float c0a = 0.f, c1a = 0.f;
        {
            U32H2 a0, cc0, a1, cc1;
            a0.u = v00.x; cc0.u = v00.y; a1.u = v00.z; cc1.u = v00.w;
            half2v h0 = __builtin_elementwise_max(xv0.h * a0.h + cc0.h, z2);
            half2v h1 = __builtin_elementwise_max(xv0.h * a1.h + cc1.h, z2);
            c0a = __builtin_amdgcn_fdot2(h0, w3q0x.h, c0a, false);
            c0a = __builtin_amdgcn_fdot2(h1, w3q0y.h, c0a, false);
            a0.u = v01.x; cc0.u = v01.y; a1.u = v01.z; cc1.u = v01.w;
            h0 = __builtin_elementwise_max(xv0.h * a0.h + cc0.h, z2);
            h1 = __builtin_elementwise_max(xv0.h * a1.h + cc1.h, z2);
            c0a = __builtin_amdgcn_fdot2(h0, w3q1x.h, c0a, false);
            c0a = __builtin_amdgcn_fdot2(h1, w3q1y.h, c0a, false);
        }
        {
            U32H2 a0, cc0, a1, cc1;
            a0.u = v10.x; cc0.u = v10.y; a1.u = v10.z; cc1.u = v10.w;
            half2v h0 = __builtin_elementwise_max(xv1.h * a0.h + cc0.h, z2);
            half2v h1 = __builtin_elementwise_max(xv1.h * a1.h + cc1.h, z2);
            c1a = __builtin_amdgcn_fdot2(h0, w3q0x.h, c1a, false);
            c1a = __builtin_amdgcn_fdot2(h1, w3q0y.h, c1a, false);
            a0.u = v11.x; cc0.u = v11.y; a1.u = v11.z; cc1.u = v11.w;
            h0 = __builtin_elementwise_max(xv1.h * a0.h + cc0.h, z2);
            h1 = __builtin_elementwise_max(xv1.h * a1.h + cc1.h, z2);
            c1a = __builtin_amdgcn_fdot2(h0, w3q1x.h, c1a, false);
            c1a = __builtin_amdgcn_fdot2(h1, w3q1y.h, c1a, false);
        }
        // DPP reduce within each 16-lane row (VALU pipe); ror -> all lanes
        c0a = DPP_ADD_F(c0a, 0xB1);
        c0a = DPP_ADD_F(c0a, 0x4E);
        c0a = DPP_ADD_F(c0a, 0x124);
        c0a = DPP_ADD_F(c0a, 0x128);
        c1a = DPP_ADD_F(c1a, 0xB1);
        c1a = DPP_ADD_F(c1a, 0x4E);
        c1a = DPP_ADD_F(c1a, 0x124);
        c1a = DPP_ADD_F(c1a, 0x128);
        if (gl == 0) {
            partial[(size_t)f * BATCH + b0] = c0a;
            partial[(size_t)f * BATCH + b1i] = c1a;
        }
    }
}

// ---------------------------------------------------------------------------
// Final reduction over 256 per-feature partials + sum of b3.
// ---------------------------------------------------------------------------
__global__ __launch_bounds__(256) void reduce_out(const float* __restrict__ partial,
                                                  const float* __restrict__ b3,
                                                  float* __restrict__ out) {
    const int b = blockIdx.x * 256 + threadIdx.x;
    float v = 0.f;
    for (int p = 0; p < FDIM; ++p) v += partial[(size_t)p * BATCH + b];
    float sb3 = 0.f;
#pragma unroll 4
    for (int f4 = 0; f4 < FDIM; f4 += 4) {
        const float4 t = *(const float4*)(b3 + f4);
        sb3 += t.x + t.y + t.z + t.w;
    }
    out[b] = v + sb3;
}

extern "C" void kernel_launch(void* const* d_in, const int* in_sizes, int n_in,
                              void* d_out, int out_size, void* d_ws, size_t ws_size,
                              hipStream_t stream) {
    const float* x  = (const float*)d_in[0];
    const float* W1 = (const float*)d_in[1];
    const float* b1 = (const float*)d_in[2];
    const float* W2 = (const float*)d_in[3];
    const float* b2 = (const float*)d_in[4];
    const float* W3 = (const float*)d_in[5];
    const float* b3 = (const float*)d_in[6];

    float* partial = (float*)d_ws;
    const size_t need = (size_t)FDIM * BATCH * 4;
    if (ws_size < need) return;  // insufficient scratch; fail visibly

    coxnam_fused<<<256, 1024, DLDS_BYTES, stream>>>(W1, b1, W2, b2, x, W3,
                                                    partial);
    reduce_out<<<BATCH / 256, 256, 0, stream>>>(partial, b3, (float*)d_out);
}